// Round 5
// baseline (190.977 us; speedup 1.0000x reference)
//
#include <hip/hip_runtime.h>
#include <math.h>

// GAT aggregation: B=8,S=512,N=32,H=256,V=100001  (npos = 4096)
// Round-15: MEASUREMENT PROBE — identical kernel to R14 (152-156 us class),
// launched 3x back-to-back. Purpose: pin the kernel's own duration K, which
// rocprof top-5 hides (all slots are 400 MB re-poison fills at 60-63 us; the
// kernel is <= 59 us). dur_us ≈ overhead + 3K, R14 gave overhead + K = 155.
//   Model B (two fills in window, K≈30):  dur ≈ 205-225 -> declare roofline.
//   Model A (one fill,  K≈90):            dur ≈ 325-345 -> attack gather MLP.
// The kernel is a pure function of its inputs (no atomics, no ws): repeated
// launches write identical bytes; fills are per-iteration harness resets and
// do not multiply with launches.

constexpr int   H     = 256;
constexpr int   NN    = 32;                  // neighbors
constexpr int   C     = NN + 1;              // max candidates (self + nbrs)
constexpr int   WPB   = 4;                   // waves per block (= per pos)
constexpr int   JMAX  = (C + WPB - 1) / WPB; // max candidates per wave = 9
constexpr int   NR    = JMAX + 1;            // batched reduction width = 10
constexpr float SLOPE = 0.2f;

__global__ __launch_bounds__(256, 6) void gat_kernel(
    const int*   __restrict__ node_ids,   // [npos]
    const int*   __restrict__ neighs,     // [npos, NN]
    const int*   __restrict__ mask,       // [npos, NN]
    const float* __restrict__ emb,        // [V, H]
    const float* __restrict__ a_w,        // [2H]
    const float* __restrict__ a_b,        // [1]
    float*       __restrict__ out)        // [npos, H]
{
  __shared__ int    sidx[WPB][64];        // per-wave compacted survivor ids
  __shared__ float  smx[WPB], ssum[WPB];  // per-wave partial m, s
  __shared__ float4 sacc[WPB][64];        // per-wave partial acc (1 KB each)

  const int pos  = blockIdx.x;
  const int wv   = threadIdx.x >> 6;
  const int lane = threadIdx.x & 63;
  const int l4   = lane << 2;

  // ---- every wave: load indices/mask, ballot-compact into own LDS slice ----
  bool active = false;
  int  my     = 0;
  if (lane == 0) {
    my = node_ids[pos];
    active = true;                               // self never masked
  } else if (lane <= NN) {
    my     = neighs[pos * NN + lane - 1];
    active = (mask[pos * NN + lane - 1] == 0);   // masked -> weight +0 -> skip
  }
  const unsigned long long bal = __ballot(active);
  const int K = (int)__popcll(bal);              // wave-uniform (SGPR)
  if (active)
    sidx[wv][(int)__popcll(bal & ((1ull << lane) - 1ull))] = my;
  // Same-wave LDS write->read: DS ops execute in order within a wave.
  const int cidx = sidx[wv][lane];               // lane k = survivor k's id
  const int swv  = __builtin_amdgcn_readfirstlane(wv);

  const float4* __restrict__ embv = (const float4*)emb; // row = H/4 float4

  // Self row (survivor 0): needed by every wave for zsrc (L1 broadcast).
  const int    iself = __builtin_amdgcn_readlane(cidx, 0);
  const float4 es    = embv[(size_t)iself * (H / 4) + lane];

  // This wave's candidate rows, all loaded upfront (independent, in flight).
  float4 buf[JMAX];
#pragma unroll
  for (int j = 0; j < JMAX; ++j) {
    const int c = swv + WPB * j;
    if (c < K) {                                          // scalar guard
      const int ic = __builtin_amdgcn_readlane(cidx, c);  // SGPR row index
      buf[j] = embv[(size_t)ic * (H / 4) + lane];
    }
  }

  const float4 aw1 = *(const float4*)(a_w + l4);        // src half of a_w
  const float4 aw2 = *(const float4*)(a_w + H + l4);    // candidate half
  const float  ab  = a_b[0];

  // Batched butterfly: zsrc + all candidate dots reduced together
  // (independent values -> DS ops pipeline instead of serializing).
  float red[NR];
  red[0] = es.x * aw1.x + es.y * aw1.y + es.z * aw1.z + es.w * aw1.w;
#pragma unroll
  for (int j = 0; j < JMAX; ++j) {
    const int c = swv + WPB * j;
    red[j + 1] = 0.f;
    if (c < K) {
      const float4 cur = buf[j];
      red[j + 1] = cur.x * aw2.x + cur.y * aw2.y +
                   cur.z * aw2.z + cur.w * aw2.w;
    }
  }
#pragma unroll
  for (int off = 32; off > 0; off >>= 1) {
#pragma unroll
    for (int t = 0; t < NR; ++t)
      red[t] += __shfl_xor(red[t], off, 64);
  }
  const float zsrc = red[0];

  // Two-pass softmax over this wave's (wave-uniform) logits.
  float m = -1e30f;
#pragma unroll
  for (int j = 0; j < JMAX; ++j) {
    const int c = swv + WPB * j;
    if (c < K) {
      const float z = zsrc + red[j + 1] + ab;
      red[j + 1] = (z > 0.f) ? z : SLOPE * z;    // LeakyReLU(0.2), in place
      m = fmaxf(m, red[j + 1]);
    }
  }
  float  s = 0.f;
  float4 acc = {0.f, 0.f, 0.f, 0.f};
#pragma unroll
  for (int j = 0; j < JMAX; ++j) {
    const int c = swv + WPB * j;
    if (c < K) {
      const float pr = __expf(red[j + 1] - m);   // uniform across lanes
      s += pr;
      const float4 cur = buf[j];
      acc.x += pr * cur.x;
      acc.y += pr * cur.y;
      acc.z += pr * cur.z;
      acc.w += pr * cur.w;
    }
  }

  // ---- block merge of the 4 partials (single barrier) ----
  sacc[wv][lane] = acc;
  if (lane == 0) { smx[wv] = m; ssum[wv] = s; }
  __syncthreads();

  if (wv == 0) {
    const float M = fmaxf(fmaxf(smx[0], smx[1]), fmaxf(smx[2], smx[3]));
    float  S = 0.f;
    float4 o = {0.f, 0.f, 0.f, 0.f};
#pragma unroll
    for (int w = 0; w < WPB; ++w) {
      const float f = __expf(smx[w] - M);  // empty wave: exp(-1e30-M) = +0
      S += ssum[w] * f;
      const float4 a = sacc[w][lane];
      o.x += f * a.x; o.y += f * a.y; o.z += f * a.z; o.w += f * a.w;
    }
    const float inv = 1.f / S;
    o.x *= inv; o.y *= inv; o.z *= inv; o.w *= inv;
    *(float4*)(out + (size_t)pos * H + l4) = o;  // coalesced 1 KB store
  }
}

extern "C" void kernel_launch(void* const* d_in, const int* in_sizes, int n_in,
                              void* d_out, int out_size, void* d_ws, size_t ws_size,
                              hipStream_t stream) {
  const int*   node_ids = (const int*)d_in[0];
  const int*   neighs   = (const int*)d_in[1];
  const int*   mask     = (const int*)d_in[2];
  const float* emb      = (const float*)d_in[3];
  const float* a_w      = (const float*)d_in[4];
  const float* a_b      = (const float*)d_in[5];
  float*       out      = (float*)d_out;

  const int npos = in_sizes[0];           // B*S = 4096
  // PROBE: 3 identical launches. dur_us ≈ overhead + 3K (R14: overhead + K).
  for (int rep = 0; rep < 3; ++rep)
    gat_kernel<<<npos, 256, 0, stream>>>(node_ids, neighs, mask, emb, a_w, a_b,
                                         out);
}

// Round 6
// 152.978 us; speedup vs baseline: 1.2484x; 1.2484x over previous
//
#include <hip/hip_runtime.h>
#include <math.h>

// GAT aggregation: B=8,S=512,N=32,H=256,V=100001  (npos = 4096)
// Round-16: FINAL — revert the R15 3x-launch probe; restore the session-best
// verified kernel (R10 structure, 152.0 us).
//
// Ceiling arithmetic established by R12-R15:
//  - dur_us window = ~130-137 us of harness re-poison (two 400 MB fills @
//    ~62 us, visible as every top-5 dispatch) + kernel K.
//  - R15 probe (3 launches): K_warm = (191-155)/2 ≈ 18 us; K_cold ≈ 18-25 us.
//  - Irreducible: ~76 MB of surviving-row gathers, ~53 MB unique from HBM
//    every iteration (400 MB poison sweeps the 256 MB L3) => floor ~11-14 us.
//  - Four structural variants (serial softmax / scalar-gather two-pass /
//    wide butterfly WPB=2 / batched WPB=4 @ 6 waves) all within ±2 us =
//    window noise. Remaining headroom ~5% of dur_us, below metric noise.
//
// Structure: one block (4 waves) per position; wave w owns survivors
// {w, w+4, ...}. Masked neighbors have softmax weight exactly +0 (exp
// underflow) and are never loaded; ~17 of 33 candidates survive.

constexpr int H    = 256;
constexpr int NN   = 32;                  // neighbors
constexpr int C    = NN + 1;              // max candidates (self + neighbors)
constexpr int WPB  = 4;                   // waves per block (= per position)
constexpr int JMAX = (C + WPB - 1) / WPB; // max candidates per wave = 9
constexpr int NR   = JMAX + 1;            // batched reduction width (zsrc + 9)
constexpr float SLOPE = 0.2f;

__global__ __launch_bounds__(256, 5) void gat_kernel(
    const int*   __restrict__ node_ids,   // [npos]
    const int*   __restrict__ neighs,     // [npos, NN]
    const int*   __restrict__ mask,       // [npos, NN]
    const float* __restrict__ emb,        // [V, H]
    const float* __restrict__ a_w,        // [2H]
    const float* __restrict__ a_b,        // [1]
    float*       __restrict__ out)        // [npos, H]
{
  __shared__ int    sidx[WPB][64];        // per-wave compacted survivor ids
  __shared__ float  smx[WPB], ssum[WPB];  // per-wave partial m, s
  __shared__ float4 sacc[WPB][64];        // per-wave partial acc (1 KB each)

  const int pos  = blockIdx.x;
  const int wv   = threadIdx.x >> 6;
  const int lane = threadIdx.x & 63;
  const int l4   = lane << 2;

  // ---- every wave: load indices/mask, ballot-compact into own LDS slice ----
  bool active = false;
  int  my     = 0;
  if (lane == 0) {
    my = node_ids[pos];
    active = true;                               // self never masked
  } else if (lane <= NN) {
    my     = neighs[pos * NN + lane - 1];
    active = (mask[pos * NN + lane - 1] == 0);   // masked -> weight +0 -> skip
  }
  const unsigned long long bal = __ballot(active);
  const int K = (int)__popcll(bal);              // wave-uniform (SGPR)
  if (active)
    sidx[wv][(int)__popcll(bal & ((1ull << lane) - 1ull))] = my;
  // Same-wave LDS write->read: DS ops execute in order within a wave.
  const int cidx = sidx[wv][lane];               // lane k = survivor k's id
  const int swv  = __builtin_amdgcn_readfirstlane(wv);

  const float4 aw1 = *(const float4*)(a_w + l4);        // src half of a_w
  const float4 aw2 = *(const float4*)(a_w + H + l4);    // candidate half
  const float  ab  = a_b[0];
  const float4* __restrict__ embv = (const float4*)emb; // row = H/4 float4

  // Self row (survivor 0): needed by every wave for zsrc (L1 broadcast).
  const int    iself = __builtin_amdgcn_readlane(cidx, 0);
  const float4 es    = embv[(size_t)iself * (H / 4) + lane];

  // This wave's candidate rows, all loaded upfront (independent, in flight).
  float4 buf[JMAX];
#pragma unroll
  for (int j = 0; j < JMAX; ++j) {
    const int c = swv + WPB * j;
    if (c < K) {                                          // scalar guard
      const int ic = __builtin_amdgcn_readlane(cidx, c);  // SGPR row index
      buf[j] = embv[(size_t)ic * (H / 4) + lane];
    }
  }

  // Batched butterfly: zsrc + all candidate dots reduced together
  // (independent values -> DS ops pipeline instead of serializing).
  float red[NR];
  red[0] = es.x * aw1.x + es.y * aw1.y + es.z * aw1.z + es.w * aw1.w;
#pragma unroll
  for (int j = 0; j < JMAX; ++j) {
    const int c = swv + WPB * j;
    red[j + 1] = 0.f;
    if (c < K) {
      const float4 cur = buf[j];
      red[j + 1] = cur.x * aw2.x + cur.y * aw2.y +
                   cur.z * aw2.z + cur.w * aw2.w;
    }
  }
#pragma unroll
  for (int off = 32; off > 0; off >>= 1) {
#pragma unroll
    for (int t = 0; t < NR; ++t)
      red[t] += __shfl_xor(red[t], off, 64);
  }
  const float zsrc = red[0];

  // Two-pass softmax over this wave's (known) logits.
  float aj[JMAX];
  float m = -1e30f;
#pragma unroll
  for (int j = 0; j < JMAX; ++j) {
    const int c = swv + WPB * j;
    if (c < K) {
      const float z = zsrc + red[j + 1] + ab;
      aj[j] = (z > 0.f) ? z : SLOPE * z;          // LeakyReLU(0.2)
      m = fmaxf(m, aj[j]);
    }
  }
  float  s = 0.f;
  float4 acc = {0.f, 0.f, 0.f, 0.f};
#pragma unroll
  for (int j = 0; j < JMAX; ++j) {
    const int c = swv + WPB * j;
    if (c < K) {
      const float pr = __expf(aj[j] - m);
      s += pr;
      const float4 cur = buf[j];
      acc.x += pr * cur.x;
      acc.y += pr * cur.y;
      acc.z += pr * cur.z;
      acc.w += pr * cur.w;
    }
  }

  // ---- block merge of the 4 partials (single barrier) ----
  sacc[wv][lane] = acc;
  if (lane == 0) { smx[wv] = m; ssum[wv] = s; }
  __syncthreads();

  if (wv == 0) {
    const float M = fmaxf(fmaxf(smx[0], smx[1]), fmaxf(smx[2], smx[3]));
    float  S = 0.f;
    float4 o = {0.f, 0.f, 0.f, 0.f};
#pragma unroll
    for (int w = 0; w < WPB; ++w) {
      const float f = __expf(smx[w] - M);  // empty wave: exp(-1e30-M) = +0
      S += ssum[w] * f;
      const float4 a = sacc[w][lane];
      o.x += f * a.x; o.y += f * a.y; o.z += f * a.z; o.w += f * a.w;
    }
    const float inv = 1.f / S;
    o.x *= inv; o.y *= inv; o.z *= inv; o.w *= inv;
    *(float4*)(out + (size_t)pos * H + l4) = o;
  }
}

extern "C" void kernel_launch(void* const* d_in, const int* in_sizes, int n_in,
                              void* d_out, int out_size, void* d_ws, size_t ws_size,
                              hipStream_t stream) {
  const int*   node_ids = (const int*)d_in[0];
  const int*   neighs   = (const int*)d_in[1];
  const int*   mask     = (const int*)d_in[2];
  const float* emb      = (const float*)d_in[3];
  const float* a_w      = (const float*)d_in[4];
  const float* a_b      = (const float*)d_in[5];
  float*       out      = (float*)d_out;

  const int npos = in_sizes[0];           // B*S = 4096
  gat_kernel<<<npos, 256, 0, stream>>>(node_ids, neighs, mask, emb, a_w, a_b,
                                       out);
}